// Round 1
// baseline (975.158 us; speedup 1.0000x reference)
//
#include <hip/hip_runtime.h>
#include <math.h>

#define BB 32
#define CC 128
#define OO 256
#define KSZ 3
#define HH 56
#define WW 56
#define HWSZ (HH*WW)            // 3136
#define NPIX (BB*HWSZ)          // 100352
#define WELEM (OO*CC*KSZ*KSZ)   // 294912
#define XELEM (BB*CC*HWSZ)      // 12845056
#define QN 65535.0f
#define QINV (1.0f/65535.0f)

// ws layout (bytes):
//      0 : maxabs |w| (uint bits)           [zeroed by memset]
//    256 : w_term[256] floats               [zeroed by memset]
//   2048 : coef[9*128] floats  layout [kk][c]
//   8192 : k_eff [9][128][256] floats (1.18 MB)
// 1187840: x_q  [B][C][H][W] floats (51.4 MB) -- only if ws_size allows
#define WTERM_OFF 256
#define COEF_OFF  2048
#define KEFF_OFF  8192
#define XQ_OFF    (KEFF_OFF + (size_t)WELEM*4)
#define WS_NEED_XQ (XQ_OFF + (size_t)XELEM*4)

__device__ __forceinline__ float quant_x(float v) {
    v = fminf(fmaxf(v, 0.0f), 1.0f);
    return rintf(v * QN) * QINV;   // rintf = round-half-even, matches np/jnp
}

// ---------- Kernel A: max |w| (tanh is monotone: max|tanh(w)| = tanh(max|w|))
__global__ void kmax_kernel(const float* __restrict__ w, unsigned* __restrict__ maxout) {
    int i = blockIdx.x * blockDim.x + threadIdx.x;
    float m = 0.0f;
    for (int idx = i; idx < WELEM; idx += gridDim.x * blockDim.x)
        m = fmaxf(m, fabsf(w[idx]));
    #pragma unroll
    for (int off = 32; off; off >>= 1)
        m = fmaxf(m, __shfl_down(m, off));
    __shared__ float red[4];
    if ((threadIdx.x & 63) == 0) red[threadIdx.x >> 6] = m;
    __syncthreads();
    if (threadIdx.x == 0) {
        m = fmaxf(fmaxf(red[0], red[1]), fmaxf(red[2], red[3]));
        atomicMax(maxout, __float_as_uint(m));  // all values >= 0: uint order == float order
    }
}

// ---------- Kernel B: build k_eff (transposed [kk][c][o]), coef, w_term
__global__ void kprep_kernel(const float* __restrict__ wt, const float* __restrict__ phases,
                             const float* __restrict__ disks, const unsigned* __restrict__ maxbits,
                             float* __restrict__ keff, float* __restrict__ coef,
                             float* __restrict__ wterm) {
    int idx = blockIdx.x * blockDim.x + threadIdx.x;  // over [o][c][kh][kw]
    if (idx >= WELEM) return;
    int kk = idx % 9;
    int c  = (idx / 9) % CC;
    int o  = idx / (9 * CC);
    float M = tanhf(__uint_as_float(*maxbits));
    float t = tanhf(wt[idx]);
    float v = t / (2.0f * M) + 0.5f;
    float wq = rintf(v * QN) * QINV;
    int pidx = c * 9 + kk;
    float s  = sinf(phases[pidx]);
    float d0 = disks[pidx * 2 + 0];
    float d1 = disks[pidx * 2 + 1];
    keff[(kk * CC + c) * OO + o] = wq * (s * (d0 + d1) * 0.5f);
    float cf = (d0 - d1) * 0.25f;
    if (o == 0) coef[kk * CC + c] = cf;
    float contrib = wq * wq * cf;
    if (contrib != 0.0f) atomicAdd(wterm + o, contrib);
}

// ---------- Kernel X: pre-quantize x (vectorized float4)
__global__ void kxq_kernel(const float4* __restrict__ x, float4* __restrict__ xq) {
    int i = blockIdx.x * blockDim.x + threadIdx.x;
    if (i >= XELEM / 4) return;
    float4 v = x[i];
    v.x = quant_x(v.x); v.y = quant_x(v.y); v.z = quant_x(v.z); v.w = quant_x(v.w);
    xq[i] = v;
}

// ---------- Kernel C: direct conv. thread = 1 pixel x 16 oc.
// PREQ=true: xsrc is pre-quantized; else quantize inline.
template <bool PREQ>
__global__ __launch_bounds__(256) void kconv_kernel(
        const float* __restrict__ xsrc, const float* __restrict__ keff,
        const float* __restrict__ coef, const float* __restrict__ wterm,
        float* __restrict__ out) {
    int t   = blockIdx.x * 256 + threadIdx.x;   // flat pixel, NPIX = 392*256 exactly
    int ocb = blockIdx.y * 16;
    int b   = t / HWSZ;
    int rem = t - b * HWSZ;
    int h   = rem / WW;
    int w   = rem - h * WW;

    float acc[16];
    #pragma unroll
    for (int i = 0; i < 16; ++i) acc[i] = 0.0f;
    float s2 = 0.0f;

    const float* xb = xsrc + (size_t)b * (CC * HWSZ);

    #pragma unroll
    for (int kh = 0; kh < 3; ++kh) {
        #pragma unroll
        for (int kw = 0; kw < 3; ++kw) {
            int ih = h + kh - 1, iw = w + kw - 1;
            bool valid = ((unsigned)ih < HH) && ((unsigned)iw < WW);
            int ihc = min(max(ih, 0), HH - 1);
            int iwc = min(max(iw, 0), WW - 1);
            const float* xp   = xb + ihc * WW + iwc;
            const float* wrow = keff + (kh * 3 + kw) * (CC * OO) + ocb;
            const float* cfp  = coef + (kh * 3 + kw) * CC;
            float fm = valid ? 1.0f : 0.0f;
            #pragma unroll 4
            for (int c = 0; c < CC; ++c) {
                float xv = xp[c * HWSZ];
                if (!PREQ) xv = quant_x(xv);
                xv *= fm;
                s2 = fmaf(xv * xv, cfp[c], s2);
                #pragma unroll
                for (int i = 0; i < 16; ++i)
                    acc[i] = fmaf(xv, wrow[c * OO + i], acc[i]);
            }
        }
    }

    float* op = out + (size_t)b * (OO * HWSZ) + (size_t)ocb * HWSZ + rem;
    #pragma unroll
    for (int i = 0; i < 16; ++i)
        op[i * HWSZ] = acc[i] + s2 + wterm[ocb + i];
}

extern "C" void kernel_launch(void* const* d_in, const int* in_sizes, int n_in,
                              void* d_out, int out_size, void* d_ws, size_t ws_size,
                              hipStream_t stream) {
    const float* x      = (const float*)d_in[0];
    const float* weight = (const float*)d_in[1];
    const float* phases = (const float*)d_in[2];
    const float* disks  = (const float*)d_in[3];
    float* out = (float*)d_out;

    char* ws = (char*)d_ws;
    unsigned* maxbits = (unsigned*)(ws + 0);
    float* wterm = (float*)(ws + WTERM_OFF);
    float* coef  = (float*)(ws + COEF_OFF);
    float* keff  = (float*)(ws + KEFF_OFF);
    float* xq    = (float*)(ws + XQ_OFF);

    // zero maxabs + w_term (ws is poisoned 0xAA before every launch)
    hipMemsetAsync(d_ws, 0, WTERM_OFF + OO * sizeof(float), stream);

    kmax_kernel<<<288, 256, 0, stream>>>(weight, maxbits);
    kprep_kernel<<<(WELEM + 255) / 256, 256, 0, stream>>>(weight, phases, disks,
                                                          maxbits, keff, coef, wterm);

    dim3 cgrid(NPIX / 256, OO / 16);
    if (ws_size >= WS_NEED_XQ) {
        kxq_kernel<<<(XELEM / 4 + 255) / 256, 256, 0, stream>>>((const float4*)x, (float4*)xq);
        kconv_kernel<true><<<cgrid, 256, 0, stream>>>(xq, keff, coef, wterm, out);
    } else {
        kconv_kernel<false><<<cgrid, 256, 0, stream>>>(x, keff, coef, wterm, out);
    }
}

// Round 2
// 385.785 us; speedup vs baseline: 2.5277x; 2.5277x over previous
//
#include <hip/hip_runtime.h>
#include <math.h>

typedef __attribute__((ext_vector_type(8))) short short8;
typedef __attribute__((ext_vector_type(4))) float floatx4;

#define BB 32
#define CC 128
#define OO 256
#define HH 56
#define WW 56
#define HWSZ 3136
#define NPIX 100352
#define WELEM 294912
#define QN 65535.0f
#define QINV (1.0f/65535.0f)

// ---- workspace layout (bytes) ----
#define MAXB_OFF   0
#define WTERM_OFF  256
#define COEF_OFF   2048                       // float [9][128]
#define KEFF_OFF   8192                       // bf16 [36 steps][2 ot][128 o][32 c] = 589824 B
#define YSQ_OFF    598016                     // float [100352] = 401408 B
#define XQP_OFF    1048576                    // bf16 [32][58][64][128] = 30408704 B
#define XQP_BYTES  30408704ull
#define WS_NEED    (XQP_OFF + XQP_BYTES)
// fallback (round-1 style) layout
#define KEFF32_OFF 8192                       // float [9*128][256] = 1179648
#define WS_NEED_FB 1187840ull

__device__ __forceinline__ float quant_x(float v) {
    v = fminf(fmaxf(v, 0.0f), 1.0f);
    return rintf(v * QN) * QINV;              // round-half-even == jnp.round
}

__device__ __forceinline__ unsigned short f2bf(float f) {
    unsigned u = __float_as_uint(f);
    u += 0x7fffu + ((u >> 16) & 1u);          // RNE
    return (unsigned short)(u >> 16);
}

__device__ __forceinline__ void gl16(const void* g, void* l) {
    __builtin_amdgcn_global_load_lds(
        (const __attribute__((address_space(1))) unsigned char*)g,
        (__attribute__((address_space(3))) unsigned char*)l, 16, 0, 0);
}

// ---------- max |w| ----------
__global__ void kmax_kernel(const float* __restrict__ w, unsigned* __restrict__ maxout) {
    int i = blockIdx.x * blockDim.x + threadIdx.x;
    float m = 0.0f;
    for (int idx = i; idx < WELEM; idx += gridDim.x * blockDim.x)
        m = fmaxf(m, fabsf(w[idx]));
    #pragma unroll
    for (int off = 32; off; off >>= 1)
        m = fmaxf(m, __shfl_down(m, off));
    __shared__ float red[4];
    if ((threadIdx.x & 63) == 0) red[threadIdx.x >> 6] = m;
    __syncthreads();
    if (threadIdx.x == 0) {
        m = fmaxf(fmaxf(red[0], red[1]), fmaxf(red[2], red[3]));
        atomicMax(maxout, __float_as_uint(m));
    }
}

// ---------- prep: bf16 k_eff in staged layout + coef + w_term ----------
__global__ void kprep_kernel(const float* __restrict__ wt, const float* __restrict__ phases,
                             const float* __restrict__ disks, const unsigned* __restrict__ maxbits,
                             unsigned short* __restrict__ kefft, float* __restrict__ coef,
                             float* __restrict__ wterm) {
    int idx = blockIdx.x * blockDim.x + threadIdx.x;   // over [o][c][kh][kw]
    if (idx >= WELEM) return;
    int kk = idx % 9;
    int c  = (idx / 9) % CC;
    int o  = idx / (9 * CC);
    float M = tanhf(__uint_as_float(*maxbits));
    float t = tanhf(wt[idx]);
    float v = t / (2.0f * M) + 0.5f;
    float wq = rintf(v * QN) * QINV;
    int pidx = c * 9 + kk;
    float s  = sinf(phases[pidx]);
    float d0 = disks[pidx * 2 + 0];
    float d1 = disks[pidx * 2 + 1];
    float kv = wq * (s * (d0 + d1) * 0.5f);
    int cs = c >> 5, ci = c & 31, ot = o >> 7, op = o & 127;
    kefft[((size_t)((kk * 4 + cs) * 2 + ot) * 128 + op) * 32 + ci] = f2bf(kv);
    float cf = (d0 - d1) * 0.25f;
    if (o == 0) coef[kk * CC + c] = cf;
    float contrib = wq * wq * cf;
    if (contrib != 0.0f) atomicAdd(wterm + o, contrib);
}

// ---------- quantize + NCHW->padded-NHWC bf16 transpose ----------
__global__ __launch_bounds__(256) void kxqpad_kernel(const float* __restrict__ x,
                                                     unsigned short* __restrict__ xqp) {
    __shared__ __align__(16) unsigned short tile[64][136];   // [hw][c], row 272 B (16-aligned)
    int t = threadIdx.x;
    int b = blockIdx.y;
    int hw0 = blockIdx.x * 64;
    const float* xb = x + (size_t)b * (CC * HWSZ) + hw0;
    #pragma unroll
    for (int rep = 0; rep < 32; ++rep) {
        int lin = rep * 256 + t;
        int c = lin >> 6, j = lin & 63;
        float v = xb[(size_t)c * HWSZ + j];                  // coalesced
        tile[j][c] = f2bf(quant_x(v));
    }
    __syncthreads();
    unsigned short* xq_b = xqp + (size_t)b * (58 * 64 * 128);
    #pragma unroll
    for (int rep = 0; rep < 4; ++rep) {
        int lin = rep * 256 + t;
        int c16 = lin & 15, j = lin >> 4;
        int hw = hw0 + j;
        int h = hw / WW, w = hw - h * WW;
        short8 v = *reinterpret_cast<const short8*>(&tile[j][c16 * 8]);
        *reinterpret_cast<short8*>(xq_b + ((size_t)((h + 1) * 64 + (w + 1))) * 128 + c16 * 8) = v;
    }
}

// ---------- y_sq = conv(x_q^2, coef) ----------
__global__ __launch_bounds__(256) void ysq_kernel(const float* __restrict__ x,
                                                  const float* __restrict__ coef,
                                                  float* __restrict__ ysq) {
    __shared__ float cf[9 * CC];
    int t = threadIdx.x;
    for (int i = t; i < 9 * CC; i += 256) cf[i] = coef[i];
    __syncthreads();
    int P = blockIdx.x * 256 + t;
    int b = P / HWSZ; int hw = P - b * HWSZ;
    int h = hw / WW;  int w = hw - h * WW;
    const float* xb = x + (size_t)b * (CC * HWSZ);
    float s2 = 0.0f;
    #pragma unroll
    for (int kk = 0; kk < 9; ++kk) {
        int dh = kk / 3 - 1, dw = kk % 3 - 1;
        int ih = h + dh, iw = w + dw;
        bool valid = ((unsigned)ih < HH) && ((unsigned)iw < WW);
        int ihc = min(max(ih, 0), HH - 1), iwc = min(max(iw, 0), WW - 1);
        const float* xp = xb + ihc * WW + iwc;
        float fm = valid ? 1.0f : 0.0f;
        const float* cp = cf + kk * CC;
        #pragma unroll 4
        for (int c = 0; c < CC; ++c) {
            float xv = quant_x(xp[(size_t)c * HWSZ]) * fm;
            s2 = fmaf(xv * xv, cp[c], s2);
        }
    }
    ysq[P] = s2;
}

// ---------- MFMA implicit-GEMM conv ----------
// A = k_eff (M = O), B = x-patches (N = pixels), K = 9*128, BK = 32.
// Block: 128 o x 128 px, 4 waves (2Mw x 2Nw), wave tile 64x64 (4x4 16x16 frags).
__global__ __launch_bounds__(256, 2) void oconv_kernel(
        const unsigned short* __restrict__ xqp,
        const unsigned short* __restrict__ keff,
        const float* __restrict__ ysq,
        const float* __restrict__ wterm,
        float* __restrict__ out) {
    __shared__ __align__(16) char smem[32768];   // [2 buf][A 8KB | B 8KB]
    const int t   = threadIdx.x;
    const int bx  = blockIdx.x;                  // pixel tile (784)
    const int oty = blockIdx.y;                  // o tile (2)

    // --- staging addresses ---
    const char* gA = (const char*)keff + (size_t)oty * 8192 + (size_t)t * 16;
    const char* xb = (const char*)xqp;
    long bb0, bb1;
    {
        int c16 = t & 3, pp = t >> 2;
        int P0 = bx * 128 + pp;
        int b0 = P0 / HWSZ, hw0 = P0 - b0 * HWSZ;
        int h0 = hw0 / WW,  w0 = hw0 - h0 * WW;
        bb0 = ((long)((b0 * 58 + h0 + 1) * 64 + (w0 + 1))) * 256 + c16 * 16;
        int P1 = P0 + 64;
        int b1 = P1 / HWSZ, hw1 = P1 - b1 * HWSZ;
        int h1 = hw1 / WW,  w1 = hw1 - h1 * WW;
        bb1 = ((long)((b1 * 58 + h1 + 1) * 64 + (w1 + 1))) * 256 + c16 * 16;
    }

    const int l15 = t & 15;
    const int kg  = (t >> 4) & 3;
    const int wid = t >> 6;
    const int wm  = wid >> 1, wn = wid & 1;
    const int aoff  = (wm * 64 + l15) * 64 + kg * 16;
    const int boff2 = 8192 + (wn * 64 + l15) * 64 + kg * 16;

    floatx4 acc[4][4];
    #pragma unroll
    for (int i = 0; i < 4; ++i)
        #pragma unroll
        for (int j = 0; j < 4; ++j) acc[i][j] = (floatx4)0.0f;

    auto stage = [&](int buf, int s) {
        char* la = smem + buf * 16384 + t * 16;
        const char* ga = gA + (size_t)s * 16384;
        gl16(ga, la);
        gl16(ga + 4096, la + 4096);
        int kk = s >> 2, cs = s & 3;
        int dh = kk / 3, dw = kk - dh * 3;
        int bo = ((dh - 1) * 64 + (dw - 1)) * 256 + cs * 64;
        char* lb = la + 8192;
        gl16(xb + bb0 + bo, lb);
        gl16(xb + bb1 + bo, lb + 4096);
    };

    auto compute = [&](int buf) {
        const char* base = smem + buf * 16384;
        short8 a[4], b[4];
        #pragma unroll
        for (int mf = 0; mf < 4; ++mf)
            a[mf] = *reinterpret_cast<const short8*>(base + aoff + mf * 1024);
        #pragma unroll
        for (int nf = 0; nf < 4; ++nf)
            b[nf] = *reinterpret_cast<const short8*>(base + boff2 + nf * 1024);
        #pragma unroll
        for (int mf = 0; mf < 4; ++mf)
            #pragma unroll
            for (int nf = 0; nf < 4; ++nf)
                acc[mf][nf] = __builtin_amdgcn_mfma_f32_16x16x32_bf16(a[mf], b[nf], acc[mf][nf], 0, 0, 0);
    };

    stage(0, 0);
    for (int s = 0; s < 36; ++s) {
        __syncthreads();                 // staging of buf(s&1) complete; prior reads drained
        if (s + 1 < 36) stage((s + 1) & 1, s + 1);
        compute(s & 1);
    }

    // --- epilogue: D row = o (row=(lane>>4)*4+reg), col = pixel (col=lane&15) ---
    float wv[4][4];
    #pragma unroll
    for (int mf = 0; mf < 4; ++mf)
        #pragma unroll
        for (int j = 0; j < 4; ++j)
            wv[mf][j] = wterm[oty * 128 + wm * 64 + mf * 16 + kg * 4 + j];

    #pragma unroll
    for (int nf = 0; nf < 4; ++nf) {
        int P = bx * 128 + wn * 64 + nf * 16 + l15;
        int b = P / HWSZ; int hw = P - b * HWSZ;
        float yv = ysq[P];
        float* op = out + (size_t)b * (OO * HWSZ) + hw;
        #pragma unroll
        for (int mf = 0; mf < 4; ++mf)
            #pragma unroll
            for (int j = 0; j < 4; ++j) {
                int o = oty * 128 + wm * 64 + mf * 16 + kg * 4 + j;
                op[(size_t)o * HWSZ] = acc[mf][nf][j] + yv + wv[mf][j];
            }
    }
}

// ================= fallback path (round-1, fp32 direct conv) =================
__global__ void kprep32_kernel(const float* __restrict__ wt, const float* __restrict__ phases,
                               const float* __restrict__ disks, const unsigned* __restrict__ maxbits,
                               float* __restrict__ keff, float* __restrict__ coef,
                               float* __restrict__ wterm) {
    int idx = blockIdx.x * blockDim.x + threadIdx.x;
    if (idx >= WELEM) return;
    int kk = idx % 9;
    int c  = (idx / 9) % CC;
    int o  = idx / (9 * CC);
    float M = tanhf(__uint_as_float(*maxbits));
    float t = tanhf(wt[idx]);
    float v = t / (2.0f * M) + 0.5f;
    float wq = rintf(v * QN) * QINV;
    int pidx = c * 9 + kk;
    float s  = sinf(phases[pidx]);
    float d0 = disks[pidx * 2 + 0];
    float d1 = disks[pidx * 2 + 1];
    keff[(kk * CC + c) * OO + o] = wq * (s * (d0 + d1) * 0.5f);
    float cf = (d0 - d1) * 0.25f;
    if (o == 0) coef[kk * CC + c] = cf;
    float contrib = wq * wq * cf;
    if (contrib != 0.0f) atomicAdd(wterm + o, contrib);
}

__global__ __launch_bounds__(256) void kconv32_kernel(
        const float* __restrict__ xsrc, const float* __restrict__ keff,
        const float* __restrict__ coef, const float* __restrict__ wterm,
        float* __restrict__ out) {
    int t   = blockIdx.x * 256 + threadIdx.x;
    int ocb = blockIdx.y * 16;
    int b   = t / HWSZ;
    int rem = t - b * HWSZ;
    int h   = rem / WW;
    int w   = rem - h * WW;
    float acc[16];
    #pragma unroll
    for (int i = 0; i < 16; ++i) acc[i] = 0.0f;
    float s2 = 0.0f;
    const float* xb = xsrc + (size_t)b * (CC * HWSZ);
    #pragma unroll
    for (int kh = 0; kh < 3; ++kh) {
        #pragma unroll
        for (int kw = 0; kw < 3; ++kw) {
            int ih = h + kh - 1, iw = w + kw - 1;
            bool valid = ((unsigned)ih < HH) && ((unsigned)iw < WW);
            int ihc = min(max(ih, 0), HH - 1);
            int iwc = min(max(iw, 0), WW - 1);
            const float* xp   = xb + ihc * WW + iwc;
            const float* wrow = keff + (kh * 3 + kw) * (CC * OO) + ocb;
            const float* cfp  = coef + (kh * 3 + kw) * CC;
            float fm = valid ? 1.0f : 0.0f;
            #pragma unroll 4
            for (int c = 0; c < CC; ++c) {
                float xv = quant_x(xp[c * HWSZ]) * fm;
                s2 = fmaf(xv * xv, cfp[c], s2);
                #pragma unroll
                for (int i = 0; i < 16; ++i)
                    acc[i] = fmaf(xv, wrow[c * OO + i], acc[i]);
            }
        }
    }
    float* op = out + (size_t)b * (OO * HWSZ) + (size_t)ocb * HWSZ + rem;
    #pragma unroll
    for (int i = 0; i < 16; ++i)
        op[i * HWSZ] = acc[i] + s2 + wterm[ocb + i];
}

// ================= host launcher =================
extern "C" void kernel_launch(void* const* d_in, const int* in_sizes, int n_in,
                              void* d_out, int out_size, void* d_ws, size_t ws_size,
                              hipStream_t stream) {
    const float* x      = (const float*)d_in[0];
    const float* weight = (const float*)d_in[1];
    const float* phases = (const float*)d_in[2];
    const float* disks  = (const float*)d_in[3];
    float* out = (float*)d_out;

    char* ws = (char*)d_ws;
    unsigned* maxbits = (unsigned*)(ws + MAXB_OFF);
    float* wterm = (float*)(ws + WTERM_OFF);
    float* coef  = (float*)(ws + COEF_OFF);

    hipMemsetAsync(ws, 0, 1280, stream);   // maxbits + wterm
    kmax_kernel<<<288, 256, 0, stream>>>(weight, maxbits);

    if (ws_size >= WS_NEED) {
        unsigned short* kefft = (unsigned short*)(ws + KEFF_OFF);
        float* ysq = (float*)(ws + YSQ_OFF);
        unsigned short* xqp = (unsigned short*)(ws + XQP_OFF);

        hipMemsetAsync(ws + XQP_OFF, 0, XQP_BYTES, stream);   // zero padding
        kprep_kernel<<<(WELEM + 255) / 256, 256, 0, stream>>>(weight, phases, disks,
                                                              maxbits, kefft, coef, wterm);
        kxqpad_kernel<<<dim3(49, BB), 256, 0, stream>>>(x, xqp);
        ysq_kernel<<<NPIX / 256, 256, 0, stream>>>(x, coef, ysq);
        oconv_kernel<<<dim3(784, 2), 256, 0, stream>>>(xqp, kefft, ysq, wterm, out);
    } else {
        float* keff32 = (float*)(ws + KEFF32_OFF);
        kprep32_kernel<<<(WELEM + 255) / 256, 256, 0, stream>>>(weight, phases, disks,
                                                                maxbits, keff32, coef, wterm);
        kconv32_kernel<<<dim3(NPIX / 256, OO / 16), 256, 0, stream>>>(x, keff32, coef, wterm, out);
    }
}

// Round 4
// 248.223 us; speedup vs baseline: 3.9286x; 1.5542x over previous
//
#include <hip/hip_runtime.h>
#include <math.h>

typedef __attribute__((ext_vector_type(8))) short short8;
typedef __attribute__((ext_vector_type(4))) float floatx4;

#define BB 32
#define CC 128
#define OO 256
#define HH 56
#define WW 56
#define HWSZ 3136
#define NPIX 100352
#define WELEM 294912
#define QN 65535.0f
#define QINV (1.0f/65535.0f)

// ---- workspace layout (bytes) ----
#define MAXB_OFF   0
#define CFLAG_OFF  128                        // uint: any coef != 0 ?
#define WTERM_OFF  256
#define COEF_OFF   2048                       // float [9][128]
#define KEFF_OFF   8192                       // bf16 fragment-order [18 steps][2 ot][16KB] = 589824 B
#define YSQ_OFF    598016                     // float [100352] = 401408 B
#define XQP_OFF    1048576                    // bf16 [32][58][64][128] = 30408704 B
#define XQP_BYTES  30408704ull
#define WS_NEED    (XQP_OFF + XQP_BYTES)
// fallback layout
#define KEFF32_OFF 8192                       // float [9*128][256] = 1179648

__device__ __forceinline__ float quant_x(float v) {
    v = fminf(fmaxf(v, 0.0f), 1.0f);
    return rintf(v * QN) * QINV;              // round-half-even == jnp.round
}

__device__ __forceinline__ unsigned short f2bf(float f) {
    unsigned u = __float_as_uint(f);
    u += 0x7fffu + ((u >> 16) & 1u);          // RNE
    return (unsigned short)(u >> 16);
}

__device__ __forceinline__ void gl16(const void* g, void* l) {
    __builtin_amdgcn_global_load_lds(
        (const __attribute__((address_space(1))) unsigned char*)g,
        (__attribute__((address_space(3))) unsigned char*)l, 16, 0, 0);
}

// ---------- max |w| ----------
__global__ void kmax_kernel(const float* __restrict__ w, unsigned* __restrict__ maxout) {
    int i = blockIdx.x * blockDim.x + threadIdx.x;
    float m = 0.0f;
    for (int idx = i; idx < WELEM; idx += gridDim.x * blockDim.x)
        m = fmaxf(m, fabsf(w[idx]));
    #pragma unroll
    for (int off = 32; off; off >>= 1)
        m = fmaxf(m, __shfl_down(m, off));
    __shared__ float red[4];
    if ((threadIdx.x & 63) == 0) red[threadIdx.x >> 6] = m;
    __syncthreads();
    if (threadIdx.x == 0) {
        m = fmaxf(fmaxf(red[0], red[1]), fmaxf(red[2], red[3]));
        atomicMax(maxout, __float_as_uint(m));
    }
}

// ---------- prep: bf16 k_eff scattered into MFMA-fragment order + coef + flag + w_term ----------
// Tile for step s (kk = s>>1, c-half = s&1), o-tile ot: 16 KB, internal byte addr:
//   ch2*8192 + wm*4096 + mf*1024 + (kg*16 + l15)*16 + e*2
// with lo=o&127: wm=lo>>6, mf=(lo>>4)&3, l15=lo&15 ; lc=c&63: ch2=lc>>5, kg=(lc>>3)&3, e=lc&7
__global__ void kprep_kernel(const float* __restrict__ wt, const float* __restrict__ phases,
                             const float* __restrict__ disks, const unsigned* __restrict__ maxbits,
                             unsigned short* __restrict__ kefft, float* __restrict__ coef,
                             unsigned* __restrict__ cflag, float* __restrict__ wterm) {
    int idx = blockIdx.x * blockDim.x + threadIdx.x;   // over [o][c][kh][kw]
    if (idx >= WELEM) return;
    int kk = idx % 9;
    int c  = (idx / 9) % CC;
    int o  = idx / (9 * CC);
    float M = tanhf(__uint_as_float(*maxbits));
    float t = tanhf(wt[idx]);
    float v = t / (2.0f * M) + 0.5f;
    float wq = rintf(v * QN) * QINV;
    int pidx = c * 9 + kk;
    float s  = sinf(phases[pidx]);
    float d0 = disks[pidx * 2 + 0];
    float d1 = disks[pidx * 2 + 1];
    float kv = wq * (s * (d0 + d1) * 0.5f);

    int step = kk * 2 + (c >> 6);
    int ot = o >> 7, lo = o & 127;
    int wm = lo >> 6, mf = (lo >> 4) & 3, l15 = lo & 15;
    int ch2 = (c >> 5) & 1, kg = (c >> 3) & 3, e = c & 7;
    size_t byte = (size_t)(step * 2 + ot) * 16384
                + ch2 * 8192 + wm * 4096 + mf * 1024 + (kg * 16 + l15) * 16 + e * 2;
    kefft[byte >> 1] = f2bf(kv);

    float cf = (d0 - d1) * 0.25f;
    if (o == 0) {
        coef[kk * CC + c] = cf;
        if (cf != 0.0f) atomicOr(cflag, 1u);
    }
    float contrib = wq * wq * cf;
    if (contrib != 0.0f) atomicAdd(wterm + o, contrib);
}

// ---------- quantize + NCHW->padded-NHWC bf16 transpose ----------
__global__ __launch_bounds__(256) void kxqpad_kernel(const float* __restrict__ x,
                                                     unsigned short* __restrict__ xqp) {
    __shared__ __align__(16) unsigned short tile[64][136];   // [hw][c]
    int t = threadIdx.x;
    int b = blockIdx.y;
    int hw0 = blockIdx.x * 64;
    const float* xb = x + (size_t)b * (CC * HWSZ) + hw0;
    #pragma unroll
    for (int rep = 0; rep < 32; ++rep) {
        int lin = rep * 256 + t;
        int c = lin >> 6, j = lin & 63;
        float v = xb[(size_t)c * HWSZ + j];                  // coalesced
        tile[j][c] = f2bf(quant_x(v));
    }
    __syncthreads();
    unsigned short* xq_b = xqp + (size_t)b * (58 * 64 * 128);
    #pragma unroll
    for (int rep = 0; rep < 4; ++rep) {
        int lin = rep * 256 + t;
        int c16 = lin & 15, j = lin >> 4;
        int hw = hw0 + j;
        int h = hw / WW, w = hw - h * WW;
        short8 v = *reinterpret_cast<const short8*>(&tile[j][c16 * 8]);
        *reinterpret_cast<short8*>(xq_b + ((size_t)((h + 1) * 64 + (w + 1))) * 128 + c16 * 8) = v;
    }
}

// ---------- y_sq = conv(x_q^2, coef); exact zero fast path when all coef==0 ----------
__global__ __launch_bounds__(256) void ysq_kernel(const float* __restrict__ x,
                                                  const float* __restrict__ coef,
                                                  const unsigned* __restrict__ cflag,
                                                  float* __restrict__ ysq) {
    int t = threadIdx.x;
    int P = blockIdx.x * 256 + t;
    if (*cflag == 0u) {            // wave-uniform: ideal disks -> y_sq is exactly 0
        ysq[P] = 0.0f;
        return;
    }
    __shared__ float cf[9 * CC];
    for (int i = t; i < 9 * CC; i += 256) cf[i] = coef[i];
    __syncthreads();
    int b = P / HWSZ; int hw = P - b * HWSZ;
    int h = hw / WW;  int w = hw - h * WW;
    const float* xb = x + (size_t)b * (CC * HWSZ);
    float s2 = 0.0f;
    #pragma unroll
    for (int kk = 0; kk < 9; ++kk) {
        int dh = kk / 3 - 1, dw = kk % 3 - 1;
        int ih = h + dh, iw = w + dw;
        bool valid = ((unsigned)ih < HH) && ((unsigned)iw < WW);
        int ihc = min(max(ih, 0), HH - 1), iwc = min(max(iw, 0), WW - 1);
        const float* xp = xb + ihc * WW + iwc;
        float fm = valid ? 1.0f : 0.0f;
        const float* cp = cf + kk * CC;
        #pragma unroll 4
        for (int c = 0; c < CC; ++c) {
            float xv = quant_x(xp[(size_t)c * HWSZ]) * fm;
            s2 = fmaf(xv * xv, cp[c], s2);
        }
    }
    ysq[P] = s2;
}

// ---------- MFMA implicit-GEMM conv ----------
// A = k_eff (M=O), B = x-patches (N=pixels), K = 9*128, BK = 64 (two 32-halves/step).
// Block: 128 o x 128 px, 4 waves (2Mw x 2Nw), wave tile 64x64 (4x4 16x16 frags).
// LDS: 2 bufs x (A 16KB | B 16KB) = 64KB; all tiles in MFMA-fragment order so every
// ds_read_b128 is wave_base + lane*16 (linear, conflict-free).
__global__ __launch_bounds__(256, 2) void oconv_kernel(
        const unsigned short* __restrict__ xqp,
        const unsigned short* __restrict__ keff,
        const float* __restrict__ ysq,
        const float* __restrict__ wterm,
        float* __restrict__ out) {
    __shared__ __align__(16) char smem[65536];
    const int t   = threadIdx.x;
    const int bx  = blockIdx.x;                  // pixel tile (784)
    const int oty = blockIdx.y;                  // o tile (2)

    const char* xb = (const char*)xqp;
    // B staging source bases: thread t serves (px, c-chunk):
    //   px = (t>>6)*16 + (t&15)  (+64 for the wn=1 region), c-bytes = ((t>>4)&3)*16
    long bb0, bb1;
    {
        int pxA  = ((t >> 6) << 4) + (t & 15);
        int cOff = ((t >> 4) & 3) * 16;
        int P0 = bx * 128 + pxA;
        int b0 = P0 / HWSZ, hw0 = P0 - b0 * HWSZ;
        int h0 = hw0 / WW,  w0 = hw0 - h0 * WW;
        bb0 = ((long)((b0 * 58 + h0 + 1) * 64 + (w0 + 1))) * 256 + cOff;
        int P1 = P0 + 64;
        int b1 = P1 / HWSZ, hw1 = P1 - b1 * HWSZ;
        int h1 = hw1 / WW,  w1 = hw1 - h1 * WW;
        bb1 = ((long)((b1 * 58 + h1 + 1) * 64 + (w1 + 1))) * 256 + cOff;
    }

    const int l15 = t & 15;
    const int kg  = (t >> 4) & 3;
    const int wid = t >> 6;
    const int wm  = wid >> 1, wn = wid & 1;
    const int lane16 = (t & 63) * 16;

    floatx4 acc[4][4];
    #pragma unroll
    for (int i = 0; i < 4; ++i)
        #pragma unroll
        for (int j = 0; j < 4; ++j) acc[i][j] = (floatx4)0.0f;

    auto stage = [&](int buf, int s) {
        char* la = smem + buf * 32768 + t * 16;
        const char* ga = (const char*)keff + (size_t)(s * 2 + oty) * 16384 + t * 16;
        gl16(ga,         la);
        gl16(ga + 4096,  la + 4096);
        gl16(ga + 8192,  la + 8192);
        gl16(ga + 12288, la + 12288);
        int kk = s >> 1;
        int dh = kk / 3, dw = kk - dh * 3;
        long bo = (long)((dh - 1) * 64 + (dw - 1)) * 256 + (s & 1) * 128;
        char* lb = la + 16384;
        gl16(xb + bb0 + bo,      lb);            // ch2=0, wn=0
        gl16(xb + bb1 + bo,      lb + 4096);     // ch2=0, wn=1
        gl16(xb + bb0 + bo + 64, lb + 8192);     // ch2=1, wn=0
        gl16(xb + bb1 + bo + 64, lb + 12288);    // ch2=1, wn=1
    };

    auto computeHalf = [&](int buf, int h) {
        const char* base = smem + buf * 32768;
        const char* ap = base + h * 8192 + wm * 4096 + lane16;
        const char* bp = base + 16384 + h * 8192 + wn * 4096 + lane16;
        short8 a[4], b[4];
        #pragma unroll
        for (int mf = 0; mf < 4; ++mf)
            a[mf] = *reinterpret_cast<const short8*>(ap + mf * 1024);
        #pragma unroll
        for (int nf = 0; nf < 4; ++nf)
            b[nf] = *reinterpret_cast<const short8*>(bp + nf * 1024);
        #pragma unroll
        for (int mf = 0; mf < 4; ++mf)
            #pragma unroll
            for (int nf = 0; nf < 4; ++nf)
                acc[mf][nf] = __builtin_amdgcn_mfma_f32_16x16x32_bf16(a[mf], b[nf], acc[mf][nf], 0, 0, 0);
    };

    stage(0, 0);
    for (int s = 0; s < 18; ++s) {
        __syncthreads();                 // drains vmcnt: buf s&1 staged; prior ds_reads done
        if (s + 1 < 18) stage((s + 1) & 1, s + 1);
        computeHalf(s & 1, 0);
        computeHalf(s & 1, 1);
    }

    // --- epilogue: D row = o (row=(lane>>4)*4+reg), col = pixel (col=lane&15) ---
    float wv[4][4];
    #pragma unroll
    for (int mf = 0; mf < 4; ++mf)
        #pragma unroll
        for (int j = 0; j < 4; ++j)
            wv[mf][j] = wterm[oty * 128 + wm * 64 + mf * 16 + kg * 4 + j];

    #pragma unroll
    for (int nf = 0; nf < 4; ++nf) {
        int P = bx * 128 + wn * 64 + nf * 16 + l15;
        int b = P / HWSZ; int hw = P - b * HWSZ;
        float yv = ysq[P];
        float* op = out + (size_t)b * (OO * HWSZ) + hw;
        #pragma unroll
        for (int mf = 0; mf < 4; ++mf)
            #pragma unroll
            for (int j = 0; j < 4; ++j) {
                int o = oty * 128 + wm * 64 + mf * 16 + kg * 4 + j;
                op[(size_t)o * HWSZ] = acc[mf][nf][j] + yv + wv[mf][j];
            }
    }
}

// ================= fallback path (fp32 direct conv) =================
__global__ void kprep32_kernel(const float* __restrict__ wt, const float* __restrict__ phases,
                               const float* __restrict__ disks, const unsigned* __restrict__ maxbits,
                               float* __restrict__ keff, float* __restrict__ coef,
                               float* __restrict__ wterm) {
    int idx = blockIdx.x * blockDim.x + threadIdx.x;
    if (idx >= WELEM) return;
    int kk = idx % 9;
    int c  = (idx / 9) % CC;
    int o  = idx / (9 * CC);
    float M = tanhf(__uint_as_float(*maxbits));
    float t = tanhf(wt[idx]);
    float v = t / (2.0f * M) + 0.5f;
    float wq = rintf(v * QN) * QINV;
    int pidx = c * 9 + kk;
    float s  = sinf(phases[pidx]);
    float d0 = disks[pidx * 2 + 0];
    float d1 = disks[pidx * 2 + 1];
    keff[(kk * CC + c) * OO + o] = wq * (s * (d0 + d1) * 0.5f);
    float cf = (d0 - d1) * 0.25f;
    if (o == 0) coef[kk * CC + c] = cf;
    float contrib = wq * wq * cf;
    if (contrib != 0.0f) atomicAdd(wterm + o, contrib);
}

__global__ __launch_bounds__(256) void kconv32_kernel(
        const float* __restrict__ xsrc, const float* __restrict__ keff,
        const float* __restrict__ coef, const float* __restrict__ wterm,
        float* __restrict__ out) {
    int t   = blockIdx.x * 256 + threadIdx.x;
    int ocb = blockIdx.y * 16;
    int b   = t / HWSZ;
    int rem = t - b * HWSZ;
    int h   = rem / WW;
    int w   = rem - h * WW;
    float acc[16];
    #pragma unroll
    for (int i = 0; i < 16; ++i) acc[i] = 0.0f;
    float s2 = 0.0f;
    const float* xb = xsrc + (size_t)b * (CC * HWSZ);
    #pragma unroll
    for (int kh = 0; kh < 3; ++kh) {
        #pragma unroll
        for (int kw = 0; kw < 3; ++kw) {
            int ih = h + kh - 1, iw = w + kw - 1;
            bool valid = ((unsigned)ih < HH) && ((unsigned)iw < WW);
            int ihc = min(max(ih, 0), HH - 1);
            int iwc = min(max(iw, 0), WW - 1);
            const float* xp   = xb + ihc * WW + iwc;
            const float* wrow = keff + (kh * 3 + kw) * (CC * OO) + ocb;
            const float* cfp  = coef + (kh * 3 + kw) * CC;
            float fm = valid ? 1.0f : 0.0f;
            #pragma unroll 4
            for (int c = 0; c < CC; ++c) {
                float xv = quant_x(xp[c * HWSZ]) * fm;
                s2 = fmaf(xv * xv, cfp[c], s2);
                #pragma unroll
                for (int i = 0; i < 16; ++i)
                    acc[i] = fmaf(xv, wrow[c * OO + i], acc[i]);
            }
        }
    }
    float* op = out + (size_t)b * (OO * HWSZ) + (size_t)ocb * HWSZ + rem;
    #pragma unroll
    for (int i = 0; i < 16; ++i)
        op[i * HWSZ] = acc[i] + s2 + wterm[ocb + i];
}

// ================= host launcher =================
extern "C" void kernel_launch(void* const* d_in, const int* in_sizes, int n_in,
                              void* d_out, int out_size, void* d_ws, size_t ws_size,
                              hipStream_t stream) {
    const float* x      = (const float*)d_in[0];
    const float* weight = (const float*)d_in[1];
    const float* phases = (const float*)d_in[2];
    const float* disks  = (const float*)d_in[3];
    float* out = (float*)d_out;

    char* ws = (char*)d_ws;
    unsigned* maxbits = (unsigned*)(ws + MAXB_OFF);
    unsigned* cflag   = (unsigned*)(ws + CFLAG_OFF);
    float* wterm = (float*)(ws + WTERM_OFF);
    float* coef  = (float*)(ws + COEF_OFF);

    hipMemsetAsync(ws, 0, 1280, stream);   // maxbits + cflag + wterm
    kmax_kernel<<<288, 256, 0, stream>>>(weight, maxbits);

    if (ws_size >= WS_NEED) {
        unsigned short* kefft = (unsigned short*)(ws + KEFF_OFF);
        float* ysq = (float*)(ws + YSQ_OFF);
        unsigned short* xqp = (unsigned short*)(ws + XQP_OFF);

        hipMemsetAsync(ws + XQP_OFF, 0, XQP_BYTES, stream);   // zero padding
        kprep_kernel<<<(WELEM + 255) / 256, 256, 0, stream>>>(weight, phases, disks,
                                                              maxbits, kefft, coef, cflag, wterm);
        kxqpad_kernel<<<dim3(49, BB), 256, 0, stream>>>(x, xqp);
        ysq_kernel<<<NPIX / 256, 256, 0, stream>>>(x, coef, cflag, ysq);
        oconv_kernel<<<dim3(784, 2), 256, 0, stream>>>(xqp, kefft, ysq, wterm, out);
    } else {
        float* keff32 = (float*)(ws + KEFF32_OFF);
        kprep32_kernel<<<(WELEM + 255) / 256, 256, 0, stream>>>(weight, phases, disks,
                                                                maxbits, keff32, coef, wterm);
        kconv32_kernel<<<dim3(NPIX / 256, OO / 16), 256, 0, stream>>>(x, keff32, coef, wterm, out);
    }
}

// Round 5
// 239.697 us; speedup vs baseline: 4.0683x; 1.0356x over previous
//
#include <hip/hip_runtime.h>
#include <math.h>

typedef __attribute__((ext_vector_type(8))) short short8;
typedef __attribute__((ext_vector_type(4))) float floatx4;

#define BB 32
#define CC 128
#define OO 256
#define HH 56
#define WW 56
#define HWSZ 3136
#define NPIX 100352
#define WELEM 294912
#define QN 65535.0f
#define QINV (1.0f/65535.0f)

// ---- workspace layout (bytes) ----
#define MAXB_OFF   0
#define CFLAG_OFF  128                        // uint: any coef != 0 ?
#define WTERM_OFF  256
#define COEF_OFF   2048                       // float [9][128]
#define KEFF_OFF   8192                       // bf16 fragment-order [36 steps][2 ot][8KB] = 589824 B
#define YSQ_OFF    598016                     // float [100352] = 401408 B
#define XQP_OFF    1048576                    // bf16 [32][58][64][128] = 30408704 B
#define XQP_BYTES  30408704ull
#define WS_NEED    (XQP_OFF + XQP_BYTES)
// fallback layout
#define KEFF32_OFF 8192                       // float [9*128][256] = 1179648

__device__ __forceinline__ float quant_x(float v) {
    v = fminf(fmaxf(v, 0.0f), 1.0f);
    return rintf(v * QN) * QINV;              // round-half-even == jnp.round
}

__device__ __forceinline__ unsigned short f2bf(float f) {
    unsigned u = __float_as_uint(f);
    u += 0x7fffu + ((u >> 16) & 1u);          // RNE
    return (unsigned short)(u >> 16);
}

__device__ __forceinline__ void gl16(const void* g, void* l) {
    __builtin_amdgcn_global_load_lds(
        (const __attribute__((address_space(1))) unsigned char*)g,
        (__attribute__((address_space(3))) unsigned char*)l, 16, 0, 0);
}

// ---------- max |w| ----------
__global__ void kmax_kernel(const float* __restrict__ w, unsigned* __restrict__ maxout) {
    int i = blockIdx.x * blockDim.x + threadIdx.x;
    float m = 0.0f;
    for (int idx = i; idx < WELEM; idx += gridDim.x * blockDim.x)
        m = fmaxf(m, fabsf(w[idx]));
    #pragma unroll
    for (int off = 32; off; off >>= 1)
        m = fmaxf(m, __shfl_down(m, off));
    __shared__ float red[4];
    if ((threadIdx.x & 63) == 0) red[threadIdx.x >> 6] = m;
    __syncthreads();
    if (threadIdx.x == 0) {
        m = fmaxf(fmaxf(red[0], red[1]), fmaxf(red[2], red[3]));
        atomicMax(maxout, __float_as_uint(m));
    }
}

// ---------- prep: bf16 k_eff scattered into MFMA-fragment order + coef + flag + w_term ----------
// BK=32: step s = kk*4 + cs (cs = c>>5), tile per (step, ot) = 8KB:
//   byte = wm*4096 + mf*1024 + (kg*16 + l15)*16 + e*2
// with lo=o&127: wm=lo>>6, mf=(lo>>4)&3, l15=lo&15 ; c&31: kg=(c>>3)&3, e=c&7
__global__ void kprep_kernel(const float* __restrict__ wt, const float* __restrict__ phases,
                             const float* __restrict__ disks, const unsigned* __restrict__ maxbits,
                             unsigned short* __restrict__ kefft, float* __restrict__ coef,
                             unsigned* __restrict__ cflag, float* __restrict__ wterm) {
    int idx = blockIdx.x * blockDim.x + threadIdx.x;   // over [o][c][kh][kw]
    if (idx >= WELEM) return;
    int kk = idx % 9;
    int c  = (idx / 9) % CC;
    int o  = idx / (9 * CC);
    float M = tanhf(__uint_as_float(*maxbits));
    float t = tanhf(wt[idx]);
    float v = t / (2.0f * M) + 0.5f;
    float wq = rintf(v * QN) * QINV;
    int pidx = c * 9 + kk;
    float s  = sinf(phases[pidx]);
    float d0 = disks[pidx * 2 + 0];
    float d1 = disks[pidx * 2 + 1];
    float kv = wq * (s * (d0 + d1) * 0.5f);

    int step = kk * 4 + (c >> 5);
    int ot = o >> 7, lo = o & 127;
    int wm = lo >> 6, mf = (lo >> 4) & 3, l15 = lo & 15;
    int kg = (c >> 3) & 3, e = c & 7;
    size_t byte = (size_t)(step * 2 + ot) * 8192
                + wm * 4096 + mf * 1024 + (kg * 16 + l15) * 16 + e * 2;
    kefft[byte >> 1] = f2bf(kv);

    float cf = (d0 - d1) * 0.25f;
    if (o == 0) {
        coef[kk * CC + c] = cf;
        if (cf != 0.0f) atomicOr(cflag, 1u);
    }
    float contrib = wq * wq * cf;
    if (contrib != 0.0f) atomicAdd(wterm + o, contrib);
}

// ---------- zero only the padding border of xqp (replaces 30MB memset) ----------
__global__ __launch_bounds__(256) void kborder_kernel(unsigned short* __restrict__ xqp) {
    int t = threadIdx.x;
    int id = blockIdx.x * 256 + t;          // [0, 9216): 576 border px * 16 chunks
    int b = blockIdx.y;
    int pxi = id >> 4, chunk = id & 15;
    int h, w;
    if (pxi < 128) { h = (pxi >> 6) * 57; w = pxi & 63; }
    else { int r = pxi - 128; h = 1 + (r >> 3); int wi = r & 7; w = wi == 0 ? 0 : 56 + wi; }
    short8 z = (short8)0;
    *reinterpret_cast<short8*>((char*)xqp + (size_t)b * 3801088ull
                               + ((size_t)(h * 64 + w)) * 256 + chunk * 16) = z;
}

// ---------- quantize + NCHW->padded-NHWC bf16 transpose ----------
__global__ __launch_bounds__(256) void kxqpad_kernel(const float* __restrict__ x,
                                                     unsigned short* __restrict__ xqp) {
    __shared__ __align__(16) unsigned short tile[64][136];   // [hw][c]
    int t = threadIdx.x;
    int b = blockIdx.y;
    int hw0 = blockIdx.x * 64;
    const float* xb = x + (size_t)b * (CC * HWSZ) + hw0;
    #pragma unroll
    for (int rep = 0; rep < 32; ++rep) {
        int lin = rep * 256 + t;
        int c = lin >> 6, j = lin & 63;
        float v = xb[(size_t)c * HWSZ + j];                  // coalesced
        tile[j][c] = f2bf(quant_x(v));
    }
    __syncthreads();
    unsigned short* xq_b = xqp + (size_t)b * (58 * 64 * 128);
    #pragma unroll
    for (int rep = 0; rep < 4; ++rep) {
        int lin = rep * 256 + t;
        int c16 = lin & 15, j = lin >> 4;
        int hw = hw0 + j;
        int h = hw / WW, w = hw - h * WW;
        short8 v = *reinterpret_cast<const short8*>(&tile[j][c16 * 8]);
        *reinterpret_cast<short8*>(xq_b + ((size_t)((h + 1) * 64 + (w + 1))) * 128 + c16 * 8) = v;
    }
}

// ---------- y_sq = conv(x_q^2, coef); exact zero fast path when all coef==0 ----------
__global__ __launch_bounds__(256) void ysq_kernel(const float* __restrict__ x,
                                                  const float* __restrict__ coef,
                                                  const unsigned* __restrict__ cflag,
                                                  float* __restrict__ ysq) {
    int t = threadIdx.x;
    int P = blockIdx.x * 256 + t;
    if (*cflag == 0u) {            // wave-uniform: ideal disks -> y_sq is exactly 0
        ysq[P] = 0.0f;
        return;
    }
    __shared__ float cf[9 * CC];
    for (int i = t; i < 9 * CC; i += 256) cf[i] = coef[i];
    __syncthreads();
    int b = P / HWSZ; int hw = P - b * HWSZ;
    int h = hw / WW;  int w = hw - h * WW;
    const float* xb = x + (size_t)b * (CC * HWSZ);
    float s2 = 0.0f;
    #pragma unroll
    for (int kk = 0; kk < 9; ++kk) {
        int dh = kk / 3 - 1, dw = kk % 3 - 1;
        int ih = h + dh, iw = w + dw;
        bool valid = ((unsigned)ih < HH) && ((unsigned)iw < WW);
        int ihc = min(max(ih, 0), HH - 1), iwc = min(max(iw, 0), WW - 1);
        const float* xp = xb + ihc * WW + iwc;
        float fm = valid ? 1.0f : 0.0f;
        const float* cp = cf + kk * CC;
        #pragma unroll 4
        for (int c = 0; c < CC; ++c) {
            float xv = quant_x(xp[(size_t)c * HWSZ]) * fm;
            s2 = fmaf(xv * xv, cp[c], s2);
        }
    }
    ysq[P] = s2;
}

// ---------- MFMA implicit-GEMM conv: BK=32, counted-vmcnt depth-2 pipeline ----------
// A = k_eff (M=O), B = x-patches (N=pixels), K = 9*128 = 36 steps of 32.
// Block: 128 o x 128 px, 4 waves (2Mw x 2Nw), wave tile 64x64 (4x4 16x16 frags).
// LDS: 2 bufs x (A 8KB | B 8KB) = 32KB. All tiles MFMA-fragment-order: every
// ds_read_b128 is wave_base + lane*16 (linear, conflict-free).
// Pipeline: batches s, s+1 in flight; wait vmcnt(4) -> barrier -> compute(s) ->
// lgkmcnt(0) -> barrier -> stage(s+2) into buffer s&1. Never vmcnt(0) in-loop.
__global__ __launch_bounds__(256, 2) void oconv_kernel(
        const unsigned short* __restrict__ xqp,
        const unsigned short* __restrict__ keff,
        const float* __restrict__ ysq,
        const float* __restrict__ wterm,
        float* __restrict__ out) {
    __shared__ __align__(16) char smem[32768];
    const int t  = threadIdx.x;
    // XCD-pair swizzle: 1568 blocks = 8 XCD chunks of 196 virtual ids;
    // virtual pair (2k,2k+1) shares the B tile and lands on one XCD.
    const int id  = blockIdx.x;
    const int swz = (id & 7) * 196 + (id >> 3);
    const int bx  = swz >> 1;                    // pixel tile (784)
    const int oty = swz & 1;                     // o tile (2)

    const char* xb = (const char*)xqp;
    long bb0, bb1;
    {
        int pxA  = ((t >> 6) << 4) + (t & 15);
        int cOff = ((t >> 4) & 3) * 16;
        int P0 = bx * 128 + pxA;
        int b0 = P0 / HWSZ, hw0 = P0 - b0 * HWSZ;
        int h0 = hw0 / WW,  w0 = hw0 - h0 * WW;
        bb0 = ((long)((b0 * 58 + h0 + 1) * 64 + (w0 + 1))) * 256 + cOff;
        int P1 = P0 + 64;
        int b1 = P1 / HWSZ, hw1 = P1 - b1 * HWSZ;
        int h1 = hw1 / WW,  w1 = hw1 - h1 * WW;
        bb1 = ((long)((b1 * 58 + h1 + 1) * 64 + (w1 + 1))) * 256 + cOff;
    }

    const int l15 = t & 15;
    const int kg  = (t >> 4) & 3;
    const int wid = t >> 6;
    const int wm  = wid >> 1, wn = wid & 1;
    const int lane16 = (t & 63) * 16;

    floatx4 acc[4][4];
    #pragma unroll
    for (int i = 0; i < 4; ++i)
        #pragma unroll
        for (int j = 0; j < 4; ++j) acc[i][j] = (floatx4)0.0f;

    auto stage = [&](int buf, int s) {
        char* la = smem + buf * 16384 + t * 16;
        const char* ga = (const char*)keff + (size_t)(s * 2 + oty) * 8192 + t * 16;
        gl16(ga,        la);            // A chunks [0,4K)
        gl16(ga + 4096, la + 4096);     // A chunks [4K,8K)
        int kk = s >> 2, cs = s & 3;
        int dh = kk / 3, dw = kk - dh * 3;
        long bo = (long)((dh - 1) * 64 + (dw - 1)) * 256 + cs * 64;
        char* lb = la + 8192;
        gl16(xb + bb0 + bo, lb);            // B wn=0
        gl16(xb + bb1 + bo, lb + 4096);     // B wn=1
    };

    auto compute = [&](int buf) {
        const char* base = smem + buf * 16384;
        const char* ap = base + wm * 4096 + lane16;
        const char* bp = base + 8192 + wn * 4096 + lane16;
        short8 a[4], b[4];
        #pragma unroll
        for (int mf = 0; mf < 4; ++mf)
            a[mf] = *reinterpret_cast<const short8*>(ap + mf * 1024);
        #pragma unroll
        for (int nf = 0; nf < 4; ++nf)
            b[nf] = *reinterpret_cast<const short8*>(bp + nf * 1024);
        #pragma unroll
        for (int mf = 0; mf < 4; ++mf)
            #pragma unroll
            for (int nf = 0; nf < 4; ++nf)
                acc[mf][nf] = __builtin_amdgcn_mfma_f32_16x16x32_bf16(a[mf], b[nf], acc[mf][nf], 0, 0, 0);
    };

    stage(0, 0);
    stage(1, 1);
    for (int s = 0; s < 36; ++s) {
        if (s < 35) { asm volatile("s_waitcnt vmcnt(4)" ::: "memory"); }
        else        { asm volatile("s_waitcnt vmcnt(0)" ::: "memory"); }
        __builtin_amdgcn_sched_barrier(0);
        __builtin_amdgcn_s_barrier();        // batch s resident for all waves
        compute(s & 1);
        asm volatile("s_waitcnt lgkmcnt(0)" ::: "memory");
        __builtin_amdgcn_sched_barrier(0);
        __builtin_amdgcn_s_barrier();        // all reads of buffer s&1 done
        if (s < 34) stage(s & 1, s + 2);     // overwrite just-read buffer
    }

    // --- epilogue: D row = o (row=(lane>>4)*4+reg), col = pixel (col=lane&15) ---
    float wv[4][4];
    #pragma unroll
    for (int mf = 0; mf < 4; ++mf)
        #pragma unroll
        for (int j = 0; j < 4; ++j)
            wv[mf][j] = wterm[oty * 128 + wm * 64 + mf * 16 + kg * 4 + j];

    #pragma unroll
    for (int nf = 0; nf < 4; ++nf) {
        int P = bx * 128 + wn * 64 + nf * 16 + l15;
        int b = P / HWSZ; int hw = P - b * HWSZ;
        float yv = ysq[P];
        float* op = out + (size_t)b * (OO * HWSZ) + hw;
        #pragma unroll
        for (int mf = 0; mf < 4; ++mf)
            #pragma unroll
            for (int j = 0; j < 4; ++j) {
                int o = oty * 128 + wm * 64 + mf * 16 + kg * 4 + j;
                op[(size_t)o * HWSZ] = acc[mf][nf][j] + yv + wv[mf][j];
            }
    }
}

// ================= fallback path (fp32 direct conv) =================
__global__ void kprep32_kernel(const float* __restrict__ wt, const float* __restrict__ phases,
                               const float* __restrict__ disks, const unsigned* __restrict__ maxbits,
                               float* __restrict__ keff, float* __restrict__ coef,
                               float* __restrict__ wterm) {
    int idx = blockIdx.x * blockDim.x + threadIdx.x;
    if (idx >= WELEM) return;
    int kk = idx % 9;
    int c  = (idx / 9) % CC;
    int o  = idx / (9 * CC);
    float M = tanhf(__uint_as_float(*maxbits));
    float t = tanhf(wt[idx]);
    float v = t / (2.0f * M) + 0.5f;
    float wq = rintf(v * QN) * QINV;
    int pidx = c * 9 + kk;
    float s  = sinf(phases[pidx]);
    float d0 = disks[pidx * 2 + 0];
    float d1 = disks[pidx * 2 + 1];
    keff[(kk * CC + c) * OO + o] = wq * (s * (d0 + d1) * 0.5f);
    float cf = (d0 - d1) * 0.25f;
    if (o == 0) coef[kk * CC + c] = cf;
    float contrib = wq * wq * cf;
    if (contrib != 0.0f) atomicAdd(wterm + o, contrib);
}

__global__ __launch_bounds__(256) void kconv32_kernel(
        const float* __restrict__ xsrc, const float* __restrict__ keff,
        const float* __restrict__ coef, const float* __restrict__ wterm,
        float* __restrict__ out) {
    int t   = blockIdx.x * 256 + threadIdx.x;
    int ocb = blockIdx.y * 16;
    int b   = t / HWSZ;
    int rem = t - b * HWSZ;
    int h   = rem / WW;
    int w   = rem - h * WW;
    float acc[16];
    #pragma unroll
    for (int i = 0; i < 16; ++i) acc[i] = 0.0f;
    float s2 = 0.0f;
    const float* xb = xsrc + (size_t)b * (CC * HWSZ);
    #pragma unroll
    for (int kh = 0; kh < 3; ++kh) {
        #pragma unroll
        for (int kw = 0; kw < 3; ++kw) {
            int ih = h + kh - 1, iw = w + kw - 1;
            bool valid = ((unsigned)ih < HH) && ((unsigned)iw < WW);
            int ihc = min(max(ih, 0), HH - 1);
            int iwc = min(max(iw, 0), WW - 1);
            const float* xp   = xb + ihc * WW + iwc;
            const float* wrow = keff + (kh * 3 + kw) * (CC * OO) + ocb;
            const float* cfp  = coef + (kh * 3 + kw) * CC;
            float fm = valid ? 1.0f : 0.0f;
            #pragma unroll 4
            for (int c = 0; c < CC; ++c) {
                float xv = quant_x(xp[c * HWSZ]) * fm;
                s2 = fmaf(xv * xv, cfp[c], s2);
                #pragma unroll
                for (int i = 0; i < 16; ++i)
                    acc[i] = fmaf(xv, wrow[c * OO + i], acc[i]);
            }
        }
    }
    float* op = out + (size_t)b * (OO * HWSZ) + (size_t)ocb * HWSZ + rem;
    #pragma unroll
    for (int i = 0; i < 16; ++i)
        op[i * HWSZ] = acc[i] + s2 + wterm[ocb + i];
}

// ================= host launcher =================
extern "C" void kernel_launch(void* const* d_in, const int* in_sizes, int n_in,
                              void* d_out, int out_size, void* d_ws, size_t ws_size,
                              hipStream_t stream) {
    const float* x      = (const float*)d_in[0];
    const float* weight = (const float*)d_in[1];
    const float* phases = (const float*)d_in[2];
    const float* disks  = (const float*)d_in[3];
    float* out = (float*)d_out;

    char* ws = (char*)d_ws;
    unsigned* maxbits = (unsigned*)(ws + MAXB_OFF);
    unsigned* cflag   = (unsigned*)(ws + CFLAG_OFF);
    float* wterm = (float*)(ws + WTERM_OFF);
    float* coef  = (float*)(ws + COEF_OFF);

    hipMemsetAsync(ws, 0, 1280, stream);   // maxbits + cflag + wterm
    kmax_kernel<<<288, 256, 0, stream>>>(weight, maxbits);

    if (ws_size >= WS_NEED) {
        unsigned short* kefft = (unsigned short*)(ws + KEFF_OFF);
        float* ysq = (float*)(ws + YSQ_OFF);
        unsigned short* xqp = (unsigned short*)(ws + XQP_OFF);

        kprep_kernel<<<(WELEM + 255) / 256, 256, 0, stream>>>(weight, phases, disks,
                                                              maxbits, kefft, coef, cflag, wterm);
        kborder_kernel<<<dim3(36, BB), 256, 0, stream>>>(xqp);
        kxqpad_kernel<<<dim3(49, BB), 256, 0, stream>>>(x, xqp);
        ysq_kernel<<<NPIX / 256, 256, 0, stream>>>(x, coef, cflag, ysq);
        oconv_kernel<<<1568, 256, 0, stream>>>(xqp, kefft, ysq, wterm, out);
    } else {
        float* keff32 = (float*)(ws + KEFF32_OFF);
        kprep32_kernel<<<(WELEM + 255) / 256, 256, 0, stream>>>(weight, phases, disks,
                                                                maxbits, keff32, coef, wterm);
        kconv32_kernel<<<dim3(NPIX / 256, OO / 16), 256, 0, stream>>>(x, keff32, coef, wterm, out);
    }
}